// Round 7
// baseline (799.721 us; speedup 1.0000x reference)
//
#include <hip/hip_runtime.h>
#include <math.h>

// Problem constants (B=4, T=1024, C=1024, T2=257, H=16, hd=64)
#define BB   4
#define TT   1024
#define CC   1024
#define TT2  257
#define NH   16
#define HD   64
typedef long long ll;

typedef __attribute__((ext_vector_type(8))) short short8;   // 8 bf16 (4 VGPR)
typedef __attribute__((ext_vector_type(4))) float f32x4;    // MFMA acc

// ---------------------------------------------------------------------------
// bf16 helpers: round-to-nearest-even convert + hi/lo split (fp32 ~= hi+lo)
// ---------------------------------------------------------------------------
__device__ __forceinline__ ushort f2bf(float f) {
    unsigned u = __float_as_uint(f);
    u += 0x7fffu + ((u >> 16) & 1u);
    return (ushort)(u >> 16);
}
__device__ __forceinline__ float bf2f(ushort h) {
    return __uint_as_float(((unsigned)h) << 16);
}
__device__ __forceinline__ void split2(float v, ushort& h, ushort& l) {
    h = f2bf(v);
    l = f2bf(v - bf2f(h));
}

__device__ __forceinline__ void async_cp16(const ushort* g, ushort* l) {
    __builtin_amdgcn_global_load_lds(
        (__attribute__((address_space(1))) void*)g,
        (__attribute__((address_space(3))) void*)l, 16, 0, 0);
}

__device__ __forceinline__ float gelu_tanh(float x) {
    float x3 = x * x * x;
    return 0.5f * x * (1.0f + tanhf(0.7978845608028654f * (x + 0.044715f * x3)));
}

// ---------------------------------------------------------------------------
// Split-bf16 MFMA GEMM.
//   MODE 1: out = (A@B^T)+bias -> split planes (lo written only for gc<loN)
//   MODE 2: out = gelu((A@B^T)+bias) -> hi plane
//   MODE 3: raw fp32 partial (split-K): grid.z = batch*S
//   APASS 2: A hi+lo (3 MFMA/pair); APASS 1: A hi only (2 MFMA/pair).
//   128x128 tile, BK=32, 4 waves, bijective XCD swizzle (m204).
// ---------------------------------------------------------------------------
template<int MODE, int APASS>
__global__ __launch_bounds__(256, 2) void gemm_sp(
    const ushort* __restrict__ AH, const ushort* __restrict__ AL, int lda,
    const ushort* __restrict__ BH, const ushort* __restrict__ BL, int ldb,
    const float* __restrict__ bias,
    float* __restrict__ outF, ushort* __restrict__ outH, ushort* __restrict__ outL,
    int M, int N, int K, int ldo,
    ll sA, ll sB, ll sO, int S, int loN)
{
    __shared__ __align__(16) ushort AsH[128 * 32];
    __shared__ __align__(16) ushort AsL[128 * 32];
    __shared__ __align__(16) ushort BsH[128 * 32];
    __shared__ __align__(16) ushort BsL[128 * 32];

    int zb, sl;
    if (MODE == 3) { zb = blockIdx.z / S; sl = blockIdx.z % S; }
    else           { zb = blockIdx.z;     sl = 0; S = 1; }
    AH += (size_t)sA * zb; if (APASS == 2) AL += (size_t)sA * zb;
    BH += (size_t)sB * zb; BL += (size_t)sB * zb;

    // XCD-aware bijective block swizzle (T1, m204)
    int gx = gridDim.x;
    int nxy = gx * gridDim.y;
    int orig = blockIdx.y * gx + blockIdx.x;
    int qq = nxy >> 3, rr = nxy & 7;
    int xcd = orig & 7, lid = orig >> 3;
    int nid = (xcd < rr ? xcd * (qq + 1) : rr * (qq + 1) + (xcd - rr) * qq) + lid;
    int r0 = (nid / gx) * 128, c0 = (nid % gx) * 128;

    int tid = threadIdx.x;
    int w = tid >> 6, lane = tid & 63;
    int g = lane >> 4, fr = lane & 15;
    int wr = w >> 1, wc = w & 1;

    const ushort* gb = nullptr;
    int ld_ = 0;
    ushort* lb = nullptr;
    bool st = true;
    if (APASS == 2) {
        if (w == 0)      { gb = AH + (size_t)r0 * lda; ld_ = lda; lb = AsH; }
        else if (w == 1) { gb = AL + (size_t)r0 * lda; ld_ = lda; lb = AsL; }
        else if (w == 2) { gb = BH + (size_t)c0 * ldb; ld_ = ldb; lb = BsH; }
        else             { gb = BL + (size_t)c0 * ldb; ld_ = ldb; lb = BsL; }
    } else {
        if (w == 0)      { gb = AH + (size_t)r0 * lda; ld_ = lda; lb = AsH; }
        else if (w == 2) { gb = BH + (size_t)c0 * ldb; ld_ = ldb; lb = BsH; }
        else if (w == 3) { gb = BL + (size_t)c0 * ldb; ld_ = ldb; lb = BsL; }
        else st = false;
    }
    const ushort* gl = st ? gb + (size_t)(lane >> 2) * ld_ + (lane & 3) * 8 : nullptr;

    f32x4 acc[4][4];
#pragma unroll
    for (int m = 0; m < 4; ++m)
#pragma unroll
        for (int n = 0; n < 4; ++n) acc[m][n] = (f32x4)0.0f;

    int nIter = K >> 5;
    int it0 = (nIter * sl) / S, it1 = (nIter * (sl + 1)) / S;
    for (int kt = it0; kt < it1; ++kt) {
        __syncthreads();
        if (st) {
            const ushort* gk = gl + (kt << 5);
#pragma unroll
            for (int i = 0; i < 8; ++i)
                async_cp16(gk + (size_t)(i * 16) * ld_, lb + i * 512);
        }
        __syncthreads();   // drains vmcnt before barrier

        short8 ah[4], al[4];
#pragma unroll
        for (int m = 0; m < 4; ++m) {
            int row = wr * 64 + m * 16 + fr;
            ah[m] = *(const short8*)(AsH + row * 32 + g * 8);
            if (APASS == 2) al[m] = *(const short8*)(AsL + row * 32 + g * 8);
        }
#pragma unroll
        for (int n = 0; n < 4; ++n) {
            int row = wc * 64 + n * 16 + fr;
            short8 bh = *(const short8*)(BsH + row * 32 + g * 8);
            short8 bl = *(const short8*)(BsL + row * 32 + g * 8);
#pragma unroll
            for (int m = 0; m < 4; ++m) {
                acc[m][n] = __builtin_amdgcn_mfma_f32_16x16x32_bf16(ah[m], bh, acc[m][n], 0, 0, 0);
                if (APASS == 2)
                    acc[m][n] = __builtin_amdgcn_mfma_f32_16x16x32_bf16(al[m], bh, acc[m][n], 0, 0, 0);
                acc[m][n] = __builtin_amdgcn_mfma_f32_16x16x32_bf16(ah[m], bl, acc[m][n], 0, 0, 0);
            }
        }
    }

    // epilogue: C/D layout col=lane&15, row=(lane>>4)*4+reg (m89-verified)
    if (MODE == 3) {
        float* po = outF + (ll)blockIdx.z * sO;
#pragma unroll
        for (int n = 0; n < 4; ++n) {
            int gc = c0 + wc * 64 + n * 16 + fr;
            if (gc >= N) continue;
#pragma unroll
            for (int m = 0; m < 4; ++m)
#pragma unroll
                for (int e = 0; e < 4; ++e) {
                    int gr = r0 + wr * 64 + m * 16 + g * 4 + e;
                    if (gr >= M) continue;
                    po[(ll)gr * ldo + gc] = acc[m][n][e];
                }
        }
    } else {
        ushort* oH = outH + (size_t)sO * zb;
        ushort* oL = outL;
#pragma unroll
        for (int n = 0; n < 4; ++n) {
            int gc = c0 + wc * 64 + n * 16 + fr;
            if (gc >= N) continue;
            float bv = bias ? bias[gc] : 0.0f;
#pragma unroll
            for (int m = 0; m < 4; ++m)
#pragma unroll
                for (int e = 0; e < 4; ++e) {
                    int gr = r0 + wr * 64 + m * 16 + g * 4 + e;
                    if (gr >= M) continue;
                    float v = acc[m][n][e] + bv;
                    if (MODE == 2) v = gelu_tanh(v);
                    ll off = (ll)gr * ldo + gc;
                    ushort hh, lo;
                    split2(v, hh, lo);
                    oH[off] = hh;
                    if (oL && gc < loN) oL[off] = lo;
                }
        }
    }
}

// ---------------------------------------------------------------------------
// Split-K reduce: out = (sum_s partial[s])*scale + bias (+res) -> fp32 or split
// ---------------------------------------------------------------------------
template<bool SPLIT>
__global__ __launch_bounds__(256) void reduce_k(
    const float* __restrict__ part, ll sOp, int S,
    const float* __restrict__ bias, const float* __restrict__ res,
    float* __restrict__ oF, ushort* __restrict__ oH, ushort* __restrict__ oL,
    int cols, int ldp, int ldo, float scale, ll sOut)
{
    int zb = blockIdx.z, r = blockIdx.y;
    int c = (blockIdx.x * 256 + threadIdx.x) * 4;
    if (c >= cols) return;
    const float* pb = part + ((ll)zb * S) * sOp + (ll)r * ldp + c;
    float4 v = *(const float4*)pb;
    for (int s = 1; s < S; ++s) {
        float4 t = *(const float4*)(pb + (ll)s * sOp);
        v.x += t.x; v.y += t.y; v.z += t.z; v.w += t.w;
    }
    v.x *= scale; v.y *= scale; v.z *= scale; v.w *= scale;
    if (bias) {
        float4 b4 = *(const float4*)(bias + c);
        v.x += b4.x; v.y += b4.y; v.z += b4.z; v.w += b4.w;
    }
    ll off = (ll)zb * sOut + (ll)r * ldo + c;
    if (SPLIT) {
        ushort4 h, l;
        split2(v.x, h.x, l.x); split2(v.y, h.y, l.y);
        split2(v.z, h.z, l.z); split2(v.w, h.w, l.w);
        *(ushort4*)(oH + off) = h;
        *(ushort4*)(oL + off) = l;
    } else {
        if (res) {
            float4 r4 = *(const float4*)(res + off);
            v.x += r4.x; v.y += r4.y; v.z += r4.z; v.w += r4.w;
        }
        *(float4*)(oF + off) = v;
    }
}

// ---------------------------------------------------------------------------
// Fused split-K reduce + residual + LayerNorm -> x (fp32) and LN split planes
// One block (256 thr) per row of CC=1024.
// ---------------------------------------------------------------------------
__global__ __launch_bounds__(256) void reduce_ln(
    const float* __restrict__ part, ll sOp, int S,
    const float* __restrict__ bias, const float* __restrict__ res,
    float* __restrict__ xout,
    const float* __restrict__ lnG, const float* __restrict__ lnB,
    ushort* __restrict__ oH, ushort* __restrict__ oL)
{
    int row = blockIdx.x, tid = threadIdx.x;
    int c = tid * 4;
    const float* pb = part + (ll)row * CC + c;
    float4 v = *(const float4*)pb;
    for (int s = 1; s < S; ++s) {
        float4 t = *(const float4*)(pb + (ll)s * sOp);
        v.x += t.x; v.y += t.y; v.z += t.z; v.w += t.w;
    }
    float4 b4 = *(const float4*)(bias + c);
    float4 r4 = *(const float4*)(res + (ll)row * CC + c);
    v.x += b4.x + r4.x; v.y += b4.y + r4.y;
    v.z += b4.z + r4.z; v.w += b4.w + r4.w;
    *(float4*)(xout + (ll)row * CC + c) = v;

    float s1 = v.x + v.y + v.z + v.w;
    float s2 = v.x * v.x + v.y * v.y + v.z * v.z + v.w * v.w;
#pragma unroll
    for (int off = 32; off >= 1; off >>= 1) {
        s1 += __shfl_xor(s1, off);
        s2 += __shfl_xor(s2, off);
    }
    __shared__ float rs[4], rss[4];
    int wave = tid >> 6;
    if ((tid & 63) == 0) { rs[wave] = s1; rss[wave] = s2; }
    __syncthreads();
    float S1 = rs[0] + rs[1] + rs[2] + rs[3];
    float S2 = rss[0] + rss[1] + rss[2] + rss[3];
    float mu   = S1 * (1.0f / CC);
    float var  = S2 * (1.0f / CC) - mu * mu;
    float rstd = rsqrtf(var + 1e-5f);
    float4 g4 = *(const float4*)(lnG + c);
    float4 e4 = *(const float4*)(lnB + c);
    float o0 = (v.x - mu) * rstd * g4.x + e4.x;
    float o1 = (v.y - mu) * rstd * g4.y + e4.y;
    float o2 = (v.z - mu) * rstd * g4.z + e4.z;
    float o3 = (v.w - mu) * rstd * g4.w + e4.w;
    ushort4 h, l;
    split2(o0, h.x, l.x); split2(o1, h.y, l.y);
    split2(o2, h.z, l.z); split2(o3, h.w, l.w);
    *(ushort4*)(oH + (size_t)row * CC + c) = h;
    *(ushort4*)(oL + (size_t)row * CC + c) = l;
}

// ---------------------------------------------------------------------------
// Fused split-K reduce + softmax(257) + split planes (ld 288, pads zeroed).
// One wave (64 thr) per row; thread t holds cols 4t..4t+3; t=63 also col 256.
// ---------------------------------------------------------------------------
__global__ __launch_bounds__(64) void reduce_sm(
    const float* __restrict__ part, ll sOp, int S, float scale,
    ushort* __restrict__ oH, ushort* __restrict__ oL)
{
    int r = blockIdx.x, zb = blockIdx.y, t = threadIdx.x;
    const float* pb = part + ((ll)zb * S) * sOp + (ll)r * 288;
    float4 v = *(const float4*)(pb + t * 4);
    float ve = (t == 63) ? pb[256] : 0.0f;
    for (int s = 1; s < S; ++s) {
        const float* ps = pb + (ll)s * sOp;
        float4 u = *(const float4*)(ps + t * 4);
        v.x += u.x; v.y += u.y; v.z += u.z; v.w += u.w;
        if (t == 63) ve += ps[256];
    }
    v.x *= scale; v.y *= scale; v.z *= scale; v.w *= scale; ve *= scale;
    float m = fmaxf(fmaxf(v.x, v.y), fmaxf(v.z, v.w));
    if (t == 63) m = fmaxf(m, ve);
#pragma unroll
    for (int off = 32; off >= 1; off >>= 1) m = fmaxf(m, __shfl_xor(m, off));
    float e0 = expf(v.x - m), e1 = expf(v.y - m);
    float e2 = expf(v.z - m), e3 = expf(v.w - m);
    float ee = (t == 63) ? expf(ve - m) : 0.0f;
    float s = e0 + e1 + e2 + e3 + ee;
#pragma unroll
    for (int off = 32; off >= 1; off >>= 1) s += __shfl_xor(s, off);
    float inv = 1.0f / s;
    ll base = ((ll)zb * TT + r) * 288;
    ushort4 h, l;
    split2(e0 * inv, h.x, l.x); split2(e1 * inv, h.y, l.y);
    split2(e2 * inv, h.z, l.z); split2(e3 * inv, h.w, l.w);
    *(ushort4*)(oH + base + t * 4) = h;
    *(ushort4*)(oL + base + t * 4) = l;
    if (t == 63) {
        ushort hh, lo;
        split2(ee * inv, hh, lo);
        oH[base + 256] = hh; oL[base + 256] = lo;
    }
    if (t >= 1 && t < 32) {           // zero pads 257..287
        oH[base + 256 + t] = 0; oL[base + 256 + t] = 0;
    }
}

// ---------------------------------------------------------------------------
// LayerNorm -> split-bf16 planes (step 1 only).
// ---------------------------------------------------------------------------
__global__ __launch_bounds__(256) void ln_split(
    const float* __restrict__ x, const float* __restrict__ gg,
    const float* __restrict__ bt, ushort* __restrict__ oH, ushort* __restrict__ oL)
{
    int row = blockIdx.x;
    int tid = threadIdx.x;
    const float4 v = *(const float4*)(x + (size_t)row * CC + tid * 4);
    float s  = v.x + v.y + v.z + v.w;
    float ss = v.x * v.x + v.y * v.y + v.z * v.z + v.w * v.w;
#pragma unroll
    for (int off = 32; off >= 1; off >>= 1) {
        s  += __shfl_xor(s, off);
        ss += __shfl_xor(ss, off);
    }
    __shared__ float rs[4], rss[4];
    int wave = tid >> 6;
    if ((tid & 63) == 0) { rs[wave] = s; rss[wave] = ss; }
    __syncthreads();
    float S  = rs[0] + rs[1] + rs[2] + rs[3];
    float SS = rss[0] + rss[1] + rss[2] + rss[3];
    float mu   = S * (1.0f / CC);
    float var  = SS * (1.0f / CC) - mu * mu;
    float rstd = rsqrtf(var + 1e-5f);
    int c = tid * 4;
    float4 g4 = *(const float4*)(gg + c);
    float4 b4 = *(const float4*)(bt + c);
    float r0 = (v.x - mu) * rstd * g4.x + b4.x;
    float r1 = (v.y - mu) * rstd * g4.y + b4.y;
    float r2 = (v.z - mu) * rstd * g4.z + b4.z;
    float r3 = (v.w - mu) * rstd * g4.w + b4.w;
    ushort4 h, l;
    split2(r0, h.x, l.x); split2(r1, h.y, l.y);
    split2(r2, h.z, l.z); split2(r3, h.w, l.w);
    *(ushort4*)(oH + (size_t)row * CC + c) = h;
    *(ushort4*)(oL + (size_t)row * CC + c) = l;
}

// ---------------------------------------------------------------------------
// Batched weight transpose+split: up to 5 jobs in one dispatch.
// W [Kd][Nd] fp32 -> oH/oL [Nd][Kd] bf16 planes.
// ---------------------------------------------------------------------------
struct WJob { const float* W; ushort* oH; ushort* oL; int Kd; int Nd; int nb; };
struct WJobs { WJob j[5]; };

__global__ __launch_bounds__(256) void wsplit_multi(WJobs jobs, int njobs)
{
    int b = blockIdx.x;
    int i = 0;
    while (i < njobs - 1 && b >= jobs.j[i].nb) { b -= jobs.j[i].nb; ++i; }
    const float* W = jobs.j[i].W;
    ushort* oH = jobs.j[i].oH;
    ushort* oL = jobs.j[i].oL;
    int Kd = jobs.j[i].Kd, Nd = jobs.j[i].Nd;
    int nbx = Nd >> 6;
    int n0 = (b % nbx) * 64, k0 = (b / nbx) * 64;

    __shared__ float t[64][65];
    int tid = threadIdx.x;
#pragma unroll
    for (int jj = 0; jj < 16; ++jj) {
        int idx = jj * 256 + tid;
        int r = idx >> 6, c = idx & 63;
        t[r][c] = W[(size_t)(k0 + r) * Nd + n0 + c];
    }
    __syncthreads();
#pragma unroll
    for (int jj = 0; jj < 16; ++jj) {
        int idx = jj * 256 + tid;
        int rn = idx >> 6, ck = idx & 63;
        float v = t[ck][rn];
        ushort h, l; split2(v, h, l);
        size_t off = (size_t)(n0 + rn) * Kd + k0 + ck;
        oH[off] = h; oL[off] = l;
    }
}

// elementwise fp32 -> split planes (img_emb)
__global__ __launch_bounds__(256) void split_rows(
    const float* __restrict__ x, ushort* __restrict__ oH, ushort* __restrict__ oL, int n4)
{
    int i = blockIdx.x * 256 + threadIdx.x;
    if (i >= n4) return;
    float4 v = ((const float4*)x)[i];
    ushort4 h, l;
    split2(v.x, h.x, l.x); split2(v.y, h.y, l.y);
    split2(v.z, h.z, l.z); split2(v.w, h.w, l.w);
    ((ushort4*)oH)[i] = h; ((ushort4*)oL)[i] = l;
}

// ---------------------------------------------------------------------------
// Self-attn V^T prep: qkvH [B*T][3072] cols 2048+h*64.. -> vT [(b*16+h)*64+d][T]
// ---------------------------------------------------------------------------
__global__ __launch_bounds__(256) void vt_self(
    const ushort* __restrict__ qkvH, ushort* __restrict__ vT)
{
    __shared__ ushort t[64][72];
    int bh = blockIdx.y, b = bh >> 4, h = bh & 15;
    int t0 = blockIdx.x * 64;
    int tid = threadIdx.x;
    int r = tid >> 2, c0 = (tid & 3) * 16;
    const ushort* src = qkvH + (size_t)(b * TT + t0 + r) * 3072 + 2048 + h * HD + c0;
    *(short8*)&t[r][c0]     = *(const short8*)(src);
    *(short8*)&t[r][c0 + 8] = *(const short8*)(src + 8);
    __syncthreads();
    ushort* dst = vT + ((size_t)bh * HD + r) * TT + t0 + c0;
#pragma unroll
    for (int i = 0; i < 16; ++i) dst[i] = t[c0 + i][r];
}

// ---------------------------------------------------------------------------
// MFMA flash causal self-attention (unchanged from round 3/4).
// ---------------------------------------------------------------------------
__global__ __launch_bounds__(256) void flash_mfma(
    const ushort* __restrict__ qkvH, const ushort* __restrict__ qkvL,
    const ushort* __restrict__ vT,
    ushort* __restrict__ oH, ushort* __restrict__ oL)
{
    __shared__ __align__(16) ushort Ks[64 * 72];
    __shared__ __align__(16) ushort Vs[64 * 72];
    __shared__ __align__(16) ushort PsH[64 * 72];
    __shared__ __align__(16) ushort PsL[64 * 72];

    int bh = blockIdx.y, b = bh >> 4, h = bh & 15;
    int qt = blockIdx.x;
    int tid = threadIdx.x;
    int w = tid >> 6, lane = tid & 63, g = lane >> 4, fr = lane & 15;

    short8 qh[2], ql[2];
    {
        size_t qoff = (size_t)(b * TT + qt * 64 + w * 16 + fr) * 3072 + h * HD + g * 8;
        qh[0] = *(const short8*)(qkvH + qoff);
        qh[1] = *(const short8*)(qkvH + qoff + 32);
        ql[0] = *(const short8*)(qkvL + qoff);
        ql[1] = *(const short8*)(qkvL + qoff + 32);
    }

    f32x4 o[4];
#pragma unroll
    for (int n = 0; n < 4; ++n) o[n] = (f32x4)0.0f;
    float mrow[4] = {-INFINITY, -INFINITY, -INFINITY, -INFINITY};
    float lrow[4] = {0.0f, 0.0f, 0.0f, 0.0f};

    int sr = tid >> 2, sc = (tid & 3) * 16;
    const ushort* kbase = qkvH + (size_t)(b * TT) * 3072 + 1024 + h * HD + sc;
    const ushort* vbase = vT + ((size_t)bh * HD + sr) * TT + sc;

    const float SC = 0.18033688011112042f;   // 0.125 * log2(e)

    for (int kt = 0; kt <= qt; ++kt) {
        __syncthreads();
        {
            const ushort* ksrc = kbase + (size_t)(kt * 64 + sr) * 3072;
            *(short8*)&Ks[sr * 72 + sc]     = *(const short8*)(ksrc);
            *(short8*)&Ks[sr * 72 + sc + 8] = *(const short8*)(ksrc + 8);
            const ushort* vsrc = vbase + kt * 64;
            *(short8*)&Vs[sr * 72 + sc]     = *(const short8*)(vsrc);
            *(short8*)&Vs[sr * 72 + sc + 8] = *(const short8*)(vsrc + 8);
        }
        __syncthreads();

        f32x4 s[4];
#pragma unroll
        for (int n = 0; n < 4; ++n) s[n] = (f32x4)0.0f;
#pragma unroll
        for (int n = 0; n < 4; ++n) {
#pragma unroll
            for (int c = 0; c < 2; ++c) {
                short8 kf = *(const short8*)&Ks[(n * 16 + fr) * 72 + c * 32 + g * 8];
                s[n] = __builtin_amdgcn_mfma_f32_16x16x32_bf16(qh[c], kf, s[n], 0, 0, 0);
                s[n] = __builtin_amdgcn_mfma_f32_16x16x32_bf16(ql[c], kf, s[n], 0, 0, 0);
            }
        }

        float pm[4] = {-INFINITY, -INFINITY, -INFINITY, -INFINITY};
        bool diag = (kt == qt);
#pragma unroll
        for (int n = 0; n < 4; ++n) {
#pragma unroll
            for (int e = 0; e < 4; ++e) {
                float sv = s[n][e] * SC;
                if (diag && (16 * n + fr) > (w * 16 + g * 4 + e)) sv = -INFINITY;
                s[n][e] = sv;
                pm[e] = fmaxf(pm[e], sv);
            }
        }
#pragma unroll
        for (int e = 0; e < 4; ++e) {
            pm[e] = fmaxf(pm[e], __shfl_xor(pm[e], 1));
            pm[e] = fmaxf(pm[e], __shfl_xor(pm[e], 2));
            pm[e] = fmaxf(pm[e], __shfl_xor(pm[e], 4));
            pm[e] = fmaxf(pm[e], __shfl_xor(pm[e], 8));
        }
        float alpha[4];
#pragma unroll
        for (int e = 0; e < 4; ++e) {
            float mn = fmaxf(mrow[e], pm[e]);
            alpha[e] = exp2f(mrow[e] - mn);
            mrow[e] = mn;
        }
        float ls[4] = {0.0f, 0.0f, 0.0f, 0.0f};
#pragma unroll
        for (int n = 0; n < 4; ++n)
#pragma unroll
            for (int e = 0; e < 4; ++e) {
                float p = exp2f(s[n][e] - mrow[e]);
                s[n][e] = p;
                ls[e] += p;
            }
#pragma unroll
        for (int e = 0; e < 4; ++e) {
            ls[e] += __shfl_xor(ls[e], 1);
            ls[e] += __shfl_xor(ls[e], 2);
            ls[e] += __shfl_xor(ls[e], 4);
            ls[e] += __shfl_xor(ls[e], 8);
            lrow[e] = lrow[e] * alpha[e] + ls[e];
        }

#pragma unroll
        for (int n = 0; n < 4; ++n)
#pragma unroll
            for (int e = 0; e < 4; ++e) {
                ushort ph, pl;
                split2(s[n][e], ph, pl);
                int idx = (w * 16 + g * 4 + e) * 72 + n * 16 + fr;
                PsH[idx] = ph; PsL[idx] = pl;
            }

#pragma unroll
        for (int n = 0; n < 4; ++n)
#pragma unroll
            for (int e = 0; e < 4; ++e) o[n][e] *= alpha[e];

        short8 paH[2], paL[2];
#pragma unroll
        for (int c = 0; c < 2; ++c) {
            paH[c] = *(const short8*)&PsH[(w * 16 + fr) * 72 + c * 32 + g * 8];
            paL[c] = *(const short8*)&PsL[(w * 16 + fr) * 72 + c * 32 + g * 8];
        }
#pragma unroll
        for (int n = 0; n < 4; ++n) {
#pragma unroll
            for (int c = 0; c < 2; ++c) {
                short8 vf = *(const short8*)&Vs[(n * 16 + fr) * 72 + c * 32 + g * 8];
                o[n] = __builtin_amdgcn_mfma_f32_16x16x32_bf16(paH[c], vf, o[n], 0, 0, 0);
                o[n] = __builtin_amdgcn_mfma_f32_16x16x32_bf16(paL[c], vf, o[n], 0, 0, 0);
            }
        }
    }

    float inv[4];
#pragma unroll
    for (int e = 0; e < 4; ++e) inv[e] = 1.0f / lrow[e];
#pragma unroll
    for (int n = 0; n < 4; ++n)
#pragma unroll
        for (int e = 0; e < 4; ++e) {
            float v = o[n][e] * inv[e];
            ushort hh, lo;
            split2(v, hh, lo);
            size_t off = (size_t)(b * TT + qt * 64 + w * 16 + g * 4 + e) * CC
                       + h * HD + n * 16 + fr;
            oH[off] = hh; oL[off] = lo;
        }
}

// ---------------------------------------------------------------------------
// Cross-attn v^T: kv split planes [1028][2048] cols 1024.. -> vT [4][1024][288]
// ---------------------------------------------------------------------------
__global__ __launch_bounds__(256) void vtrans(
    const ushort* __restrict__ kvH, const ushort* __restrict__ kvL,
    ushort* __restrict__ vTH, ushort* __restrict__ vTL)
{
    __shared__ ushort tH[32][34], tL[32][34];
    int z = blockIdx.z;
    int kk0 = blockIdx.x * 32, c0 = blockIdx.y * 32;
    int tid = threadIdx.x;
    int r = tid >> 5, c = tid & 31;
#pragma unroll
    for (int p = 0; p < 4; ++p) {
        int kk = kk0 + r + 8 * p;
        bool ok = kk < TT2;
        size_t src = (size_t)(z * TT2 + (ok ? kk : 0)) * 2048 + CC + c0 + c;
        tH[r + 8 * p][c] = ok ? kvH[src] : (ushort)0;
        tL[r + 8 * p][c] = ok ? kvL[src] : (ushort)0;
    }
    __syncthreads();
#pragma unroll
    for (int p = 0; p < 4; ++p) {
        int cc = c0 + r + 8 * p;
        size_t dst = ((size_t)z * CC + cc) * 288 + kk0 + c;
        vTH[dst] = tH[c][r + 8 * p];
        vTL[dst] = tL[c][r + 8 * p];
    }
}

__global__ __launch_bounds__(256) void copy4_kernel(
    const float4* __restrict__ src, float4* __restrict__ dst, int n4)
{
    int i = blockIdx.x * blockDim.x + threadIdx.x;
    if (i < n4) dst[i] = src[i];
}

extern "C" void kernel_launch(void* const* d_in, const int* in_sizes, int n_in,
                              void* d_out, int out_size, void* d_ws, size_t ws_size,
                              hipStream_t stream)
{
    const float* text_emb    = (const float*)d_in[0];
    const float* img_emb     = (const float*)d_in[1];
    const float* ln1_g       = (const float*)d_in[2];
    const float* ln1_b       = (const float*)d_in[3];
    const float* ln2_g       = (const float*)d_in[4];
    const float* ln2_b       = (const float*)d_in[5];
    const float* ln3_g       = (const float*)d_in[6];
    const float* ln3_b       = (const float*)d_in[7];
    const float* qkv_w       = (const float*)d_in[8];
    const float* qkv_b       = (const float*)d_in[9];
    const float* attn_proj_w = (const float*)d_in[10];
    const float* attn_proj_b = (const float*)d_in[11];
    const float* ca_q_w      = (const float*)d_in[12];
    const float* ca_q_b      = (const float*)d_in[13];
    const float* ca_kv_w     = (const float*)d_in[14];
    const float* ca_kv_b     = (const float*)d_in[15];
    const float* ca_proj_w   = (const float*)d_in[16];
    const float* ca_proj_b   = (const float*)d_in[17];
    const float* mlp_fc_w    = (const float*)d_in[18];
    const float* mlp_fc_b    = (const float*)d_in[19];
    const float* mlp_proj_w  = (const float*)d_in[20];
    const float* mlp_proj_b  = (const float*)d_in[21];

    const int M1 = BB * TT;   // 4096
    const int Mkv = BB * TT2; // 1028
    const ll MB = 1ll << 20;

    // ---- workspace arena (112 MB; 113.3 MB proven available in round 1) ----
    char* base = (char*)d_ws;
    ushort* WH = (ushort*)base;                 // 16 MB: batched weight hi-planes
    ushort* WL = (ushort*)(base + 16 * MB);     // 16 MB: lo-planes
    // per-weight plane offsets (elements)
    const size_t oQKV = 0, oATT = 3145728, oCAQ = 4194304, oCKV = 5242880, oCPR = 7340032;
    const size_t oFC = 0, oPRJ = 4194304;
    char* big = base + 32 * MB;                 // 64 MB multi-use
    ushort* qkvH = (ushort*)big;                             // 0..24
    ushort* qkvL = (ushort*)(big + 24 * MB);                 // 24..48
    ushort* vTs  = (ushort*)(big + 48 * MB);                 // 48..56
    float*  P4   = (float*)big;                              // 0..64 (S=4)
    ushort* qH   = (ushort*)big;                             // 0..8
    ushort* qL   = (ushort*)(big + 8 * MB);                  // 8..16
    float*  P6   = (float*)(big + 16 * MB);                  // 16..48 (S=2)
    ushort* kvH  = (ushort*)(big + 16 * MB);                 // 16..21
    ushort* kvL  = (ushort*)(big + 21 * MB);                 // 21..26
    float*  P7   = (float*)(big + 26 * MB);                  // 26..51.3 (S=3)
    ushort* imgH = (ushort*)(big + 58 * MB);                 // 58..61
    ushort* imgL = (ushort*)(big + 61 * MB);                 // 61..64
    ushort* vTH  = (ushort*)(big + 26 * MB);                 // 26..29
    ushort* vTL  = (ushort*)(big + 29 * MB);                 // 29..32
    float*  P9   = (float*)(big + 37 * MB);                  // 37..56 (S=4)
    ushort* attH = (ushort*)big;                             // 0..2.4
    ushort* attL = (ushort*)(big + 3 * MB);                  // 3..5.4
    float*  P11  = (float*)(big + 32 * MB);                  // 32..64 (S=2)
    float*  P12  = (float*)big;                              // 0..64 (S=4)
    ushort* hH   = (ushort*)big;                             // 0..32
    float*  P15  = (float*)(big + 32 * MB);                  // 32..64 (S=2)
    char* actA = base + 96 * MB;
    ushort* aH = (ushort*)actA;                              // 96..104
    ushort* aL = (ushort*)(actA + 8 * MB);                   // 104..112

    float* out_x   = (float*)d_out;
    float* out_img = out_x + (size_t)M1 * CC;

    // 0. batch-A weight conversion (5 weights, one dispatch)
    {
        WJobs ja;
        ja.j[0] = { qkv_w,       WH + oQKV, WL + oQKV, 1024, 3072, 768 };
        ja.j[1] = { attn_proj_w, WH + oATT, WL + oATT, 1024, 1024, 256 };
        ja.j[2] = { ca_q_w,      WH + oCAQ, WL + oCAQ, 1024, 1024, 256 };
        ja.j[3] = { ca_kv_w,     WH + oCKV, WL + oCKV, 1024, 2048, 512 };
        ja.j[4] = { ca_proj_w,   WH + oCPR, WL + oCPR, 1024, 1024, 256 };
        wsplit_multi<<<dim3(2048), 256, 0, stream>>>(ja, 5);
    }

    // 1. ln1(text) -> aH/aL
    ln_split<<<dim3(M1), 256, 0, stream>>>(text_emb, ln1_g, ln1_b, aH, aL);

    // 2. qkv = ln1 @ qkv_w + b -> split planes (lo only for Q cols)
    gemm_sp<1, 2><<<dim3(24, 32, 1), 256, 0, stream>>>(
        aH, aL, CC, WH + oQKV, WL + oQKV, CC, qkv_b, nullptr, qkvH, qkvL,
        M1, 3 * CC, CC, 3 * CC, 0, 0, 0, 1, 1024);

    // 2b. V^T prep for self-attn
    vt_self<<<dim3(TT / 64, BB * NH), 256, 0, stream>>>(qkvH, vTs);

    // 3. MFMA flash attention -> aH/aL
    flash_mfma<<<dim3(TT / 64, BB * NH), 256, 0, stream>>>(qkvH, qkvL, vTs, aH, aL);

    // 4+5. x = text + attn@proj + b ; ln3(x) -> aH/aL   (split-K=4, fused reduce+LN)
    gemm_sp<3, 2><<<dim3(8, 32, 4), 256, 0, stream>>>(
        aH, aL, CC, WH + oATT, WL + oATT, CC, nullptr, P4, nullptr, nullptr,
        M1, CC, CC, CC, 0, 0, (ll)M1 * CC, 4, 0);
    reduce_ln<<<dim3(M1), 256, 0, stream>>>(
        P4, (ll)M1 * CC, 4, attn_proj_b, text_emb, out_x, ln3_g, ln3_b, aH, aL);

    // 6. q = ln3 @ ca_q_w + b -> split qH/qL   (split-K=2)
    gemm_sp<3, 2><<<dim3(8, 32, 2), 256, 0, stream>>>(
        aH, aL, CC, WH + oCAQ, WL + oCAQ, CC, nullptr, P6, nullptr, nullptr,
        M1, CC, CC, CC, 0, 0, (ll)M1 * CC, 2, 0);
    reduce_k<true><<<dim3(1, M1, 1), 256, 0, stream>>>(
        P6, (ll)M1 * CC, 2, ca_q_b, nullptr, nullptr, qH, qL,
        CC, CC, CC, 1.0f, 0);

    // 7. kv = img @ ca_kv_w + b -> split kvH/kvL [1028][2048]  (split-K=3)
    split_rows<<<dim3(Mkv), 256, 0, stream>>>(img_emb, imgH, imgL, Mkv * CC / 4);
    gemm_sp<3, 2><<<dim3(16, 9, 3), 256, 0, stream>>>(
        imgH, imgL, CC, WH + oCKV, WL + oCKV, CC, nullptr, P7, nullptr, nullptr,
        Mkv, 2 * CC, CC, 2 * CC, 0, 0, (ll)Mkv * 2 * CC, 3, 0);
    reduce_k<true><<<dim3(2, Mkv, 1), 256, 0, stream>>>(
        P7, (ll)Mkv * 2 * CC, 3, ca_kv_b, nullptr, nullptr, kvH, kvL,
        2 * CC, 2 * CC, 2 * CC, 1.0f, 0);

    // 8. cross v^T -> vTH/vTL [4][1024][288]
    vtrans<<<dim3(9, 32, BB), 256, 0, stream>>>(kvH, kvL, vTH, vTL);

    // 9+10. att = softmax((q @ k^T)/32) -> split attH/attL  (split-K=4, fused)
    gemm_sp<3, 2><<<dim3(3, 8, BB * 4), 256, 0, stream>>>(
        qH, qL, CC, kvH, kvL, 2 * CC, nullptr, P9, nullptr, nullptr,
        TT, 288, CC, 288, (ll)TT * CC, (ll)TT2 * 2 * CC, (ll)TT * 288, 4, 0);
    reduce_sm<<<dim3(TT, BB), 64, 0, stream>>>(
        P9, (ll)TT * 288, 4, 0.03125f, attH, attL);

    // 11. caout = att @ v (batched, K=288, split-K=2) -> split aH/aL
    gemm_sp<3, 2><<<dim3(8, 8, BB * 2), 256, 0, stream>>>(
        attH, attL, 288, vTH, vTL, 288, nullptr, P11, nullptr, nullptr,
        TT, CC, 288, CC, (ll)TT * 288, (ll)CC * 288, (ll)TT * CC, 2, 0);
    reduce_k<true><<<dim3(1, TT, BB), 256, 0, stream>>>(
        P11, (ll)TT * CC, 2, nullptr, nullptr, nullptr, aH, aL,
        CC, CC, CC, 1.0f, (ll)TT * CC);

    // 12+13. x += caout@ca_proj + b ; ln2(x) -> aH/aL   (split-K=4, fused)
    gemm_sp<3, 2><<<dim3(8, 32, 4), 256, 0, stream>>>(
        aH, aL, CC, WH + oCPR, WL + oCPR, CC, nullptr, P12, nullptr, nullptr,
        M1, CC, CC, CC, 0, 0, (ll)M1 * CC, 4, 0);
    // batch-B weight conversion (after gemm12 consumed ca_proj planes)
    {
        WJobs jb;
        jb.j[0] = { mlp_fc_w,   WH + oFC,  WL + oFC,  1024, 4096, 1024 };
        jb.j[1] = { mlp_proj_w, WH + oPRJ, WL + oPRJ, 4096, 1024, 1024 };
        jb.j[2] = jb.j[0]; jb.j[3] = jb.j[0]; jb.j[4] = jb.j[0];
        wsplit_multi<<<dim3(2048), 256, 0, stream>>>(jb, 2);
    }
    reduce_ln<<<dim3(M1), 256, 0, stream>>>(
        P12, (ll)M1 * CC, 4, ca_proj_b, out_x, out_x, ln2_g, ln2_b, aH, aL);

    // 14. h = gelu(ln2 @ fc_w + b) -> hH (hi plane only)
    gemm_sp<2, 2><<<dim3(32, 32, 1), 256, 0, stream>>>(
        aH, aL, CC, WH + oFC, WL + oFC, CC, mlp_fc_b, nullptr, hH, nullptr,
        M1, 4 * CC, CC, 4 * CC, 0, 0, 0, 1, 0);

    // 15. x += h @ mlp_proj_w + b   (A hi-only, split-K=2)
    gemm_sp<3, 1><<<dim3(8, 32, 2), 256, 0, stream>>>(
        hH, nullptr, 4 * CC, WH + oPRJ, WL + oPRJ, 4 * CC, nullptr, P15, nullptr, nullptr,
        M1, CC, 4 * CC, CC, 0, 0, (ll)M1 * CC, 2, 0);
    reduce_k<false><<<dim3(1, M1, 1), 256, 0, stream>>>(
        P15, (ll)M1 * CC, 2, mlp_proj_b, out_x, out_x, nullptr, nullptr,
        CC, CC, CC, 1.0f, 0);

    // 16. out_img = img_emb
    {
        int n4 = (BB * TT2 * CC) / 4;
        copy4_kernel<<<dim3((n4 + 255) / 256), 256, 0, stream>>>(
            (const float4*)img_emb, (float4*)out_img, n4);
    }
}